// Round 10
// baseline (3280.773 us; speedup 1.0000x reference)
//
#include <hip/hip_runtime.h>

#define BB 32
#define TT 512
#define INW 256
#define HH 1024
#define OUTW 256
#define SLOT 32768  // ushorts per ring slot; layout [64 chunks][32 b][16 j]
// 3H = 3072

typedef __attribute__((ext_vector_type(8))) short short8;
typedef __attribute__((ext_vector_type(4))) float floatx4;
typedef __attribute__((ext_vector_type(4))) unsigned int uint4v;

// Sentinel: bf16 +inf. Real h values satisfy |h| < 1 (tanh/sigmoid
// contraction), so a ring dword (two bf16 h) never equals 0x7F807F80.
#define SENT 0x7F807F80u

// LDS reduce swizzle: XOR dword-index bits 2-3 with bits 5-6 (source lane).
#define RSWZ(i) ((i) ^ ((((i) >> 5) & 3) << 2))

__device__ __forceinline__ unsigned short f2bf(float f) {
    unsigned int u = __float_as_uint(f);
    u = (u + 0x7fffu + ((u >> 16) & 1u)) >> 16;
    return (unsigned short)u;
}
__device__ __forceinline__ float bf2f(unsigned short h) {
    return __uint_as_float(((unsigned int)h) << 16);
}
__device__ __forceinline__ float fast_tanh(float x) {
    return 2.f / (1.f + __expf(-2.f * x)) - 1.f;
}
__device__ __forceinline__ float tree8(const float* p) {
    return ((p[0] + p[1]) + (p[2] + p[3])) + ((p[4] + p[5]) + (p[6] + p[7]));
}

__global__ void cast_f32_bf16(const float* __restrict__ src,
                              unsigned short* __restrict__ dst, int n) {
    int i = blockIdx.x * blockDim.x + threadIdx.x;
    int stride = gridDim.x * blockDim.x;
    for (; i < n; i += stride) dst[i] = f2bf(src[i]);
}

__global__ void fill_sent(uint4v* __restrict__ dst, size_t n4) {
    size_t i = (size_t)blockIdx.x * blockDim.x + threadIdx.x;
    size_t stride = (size_t)gridDim.x * blockDim.x;
    uint4v v = {SENT, SENT, SENT, SENT};
    for (; i < n4; i += stride) dst[i] = v;
}

// C_bf16[M x 3072] = X_bf16[M x K] @ W_bf16[3072 x K]^T + bias_f32
template <int K>
__global__ __launch_bounds__(256) void gemm_gx(const unsigned short* __restrict__ X,
                                               const unsigned short* __restrict__ W,
                                               const float* __restrict__ bias,
                                               unsigned short* __restrict__ Cout) {
    __shared__ __align__(16) unsigned short As[64 * 40];
    __shared__ __align__(16) unsigned short Bs[64 * 40];
    int bid = blockIdx.x;
    int tn = bid % 48, tm = bid / 48;
    int tid = threadIdx.x;
    int lane = tid & 63, wv = tid >> 6;
    int wm = wv >> 1, wn = wv & 1;
    int l15 = lane & 15, q = lane >> 4;
    floatx4 acc[2][2] = {};
    int r = tid >> 2, kq = (tid & 3) * 8;
    const unsigned short* xrow = X + (size_t)(tm * 64 + r) * K;
    const unsigned short* wrow = W + (size_t)(tn * 64 + r) * K;
    const int NK = K / 32;
    for (int kk = 0; kk < NK; ++kk) {
        int k0 = kk * 32;
        *(short8*)&As[r * 40 + kq] = *(const short8*)&xrow[k0 + kq];
        *(short8*)&Bs[r * 40 + kq] = *(const short8*)&wrow[k0 + kq];
        __syncthreads();
        short8 a0 = *(const short8*)&As[(wm * 32 + l15) * 40 + q * 8];
        short8 a1 = *(const short8*)&As[(wm * 32 + 16 + l15) * 40 + q * 8];
        short8 b0 = *(const short8*)&Bs[(wn * 32 + l15) * 40 + q * 8];
        short8 b1 = *(const short8*)&Bs[(wn * 32 + 16 + l15) * 40 + q * 8];
        acc[0][0] = __builtin_amdgcn_mfma_f32_16x16x32_bf16(a0, b0, acc[0][0], 0, 0, 0);
        acc[0][1] = __builtin_amdgcn_mfma_f32_16x16x32_bf16(a0, b1, acc[0][1], 0, 0, 0);
        acc[1][0] = __builtin_amdgcn_mfma_f32_16x16x32_bf16(a1, b0, acc[1][0], 0, 0, 0);
        acc[1][1] = __builtin_amdgcn_mfma_f32_16x16x32_bf16(a1, b1, acc[1][1], 0, 0, 0);
        __syncthreads();
    }
    for (int mi = 0; mi < 2; ++mi)
        for (int ni = 0; ni < 2; ++ni) {
            int col = tn * 64 + wn * 32 + ni * 16 + l15;
            float bv = bias[col];
            int row0 = tm * 64 + wm * 32 + mi * 16 + q * 4;
            for (int rr = 0; rr < 4; ++rr) {
                Cout[(size_t)(row0 + rr) * 3072 + col] = f2bf(acc[mi][ni][rr] + bv);
            }
        }
}

// Verified spin-fetch of 8 A-fragment pairs -- the FULL 16 KB K-slice issued
// in ONE batch (single coherent round trip when data is ready; R19's
// half-split added a serial RT and regressed). Bypass loads are the only
// synchronization: retry until no dword is the sentinel.
__device__ __forceinline__ void spin_load8(const unsigned short* base, int kbase,
                                           int l15, int q, uint4v r0[8],
                                           uint4v r1[8]) {
    const unsigned short* ap[8];
#pragma unroll
    for (int s = 0; s < 8; ++s) {
        int k = kbase + s * 32 + q * 8;
        ap[s] = base + ((k >> 4) << 9) + (l15 << 4) + (k & 15);
    }
    while (true) {
#pragma unroll
        for (int s = 0; s < 8; ++s) {
            asm volatile("global_load_dwordx4 %0, %1, off sc0 sc1"
                         : "=&v"(r0[s]) : "v"(ap[s]));
            asm volatile("global_load_dwordx4 %0, %1, off offset:512 sc0 sc1"
                         : "=&v"(r1[s]) : "v"(ap[s]));
        }
        asm volatile("s_waitcnt vmcnt(0)"
                     : "+v"(r0[0]), "+v"(r0[1]), "+v"(r0[2]), "+v"(r0[3]),
                       "+v"(r0[4]), "+v"(r0[5]), "+v"(r0[6]), "+v"(r0[7]),
                       "+v"(r1[0]), "+v"(r1[1]), "+v"(r1[2]), "+v"(r1[3]),
                       "+v"(r1[4]), "+v"(r1[5]), "+v"(r1[6]), "+v"(r1[7])
                     :: "memory");
        unsigned bad = 0;
#pragma unroll
        for (int s = 0; s < 8; ++s) {
            bad |= (unsigned)(r0[s][0] == SENT) | (unsigned)(r0[s][1] == SENT) |
                   (unsigned)(r0[s][2] == SENT) | (unsigned)(r0[s][3] == SENT);
            bad |= (unsigned)(r1[s][0] == SENT) | (unsigned)(r1[s][1] == SENT) |
                   (unsigned)(r1[s][2] == SENT) | (unsigned)(r1[s][3] == SENT);
        }
        if (!__any((int)bad)) break;
    }
}

__device__ __forceinline__ void mfma8(const uint4v r0[8], const uint4v r1[8],
                                      const short8 Wr[8], const short8 Wz[8],
                                      const short8 Wn[8], floatx4 acc[6]) {
#pragma unroll
    for (int s = 0; s < 8; ++s) {
        short8 a0 = __builtin_bit_cast(short8, r0[s]);
        short8 a1 = __builtin_bit_cast(short8, r1[s]);
        acc[0] = __builtin_amdgcn_mfma_f32_16x16x32_bf16(a0, Wr[s], acc[0], 0, 0, 0);
        acc[1] = __builtin_amdgcn_mfma_f32_16x16x32_bf16(a0, Wz[s], acc[1], 0, 0, 0);
        acc[2] = __builtin_amdgcn_mfma_f32_16x16x32_bf16(a0, Wn[s], acc[2], 0, 0, 0);
        acc[3] = __builtin_amdgcn_mfma_f32_16x16x32_bf16(a1, Wr[s], acc[3], 0, 0, 0);
        acc[4] = __builtin_amdgcn_mfma_f32_16x16x32_bf16(a1, Wz[s], acc[4], 0, 0, 0);
        acc[5] = __builtin_amdgcn_mfma_f32_16x16x32_bf16(a1, Wn[s], acc[5], 0, 0, 0);
    }
}

// Hoist a 3-gate weight slice directly from the f32 source (read once at
// kernel start; deletes three cast kernels from the launch tail). RNE
// rounding is bit-identical to cast_f32_bf16.
__device__ __forceinline__ short8 pack8(const float* p) {
    short8 o;
#pragma unroll
    for (int i = 0; i < 8; ++i) o[i] = (short)f2bf(p[i]);
    return o;
}
__device__ __forceinline__ void hoist_w_f32(const float* wsrc, int j0, int l15,
                                            int q, int kbase, short8 Wr[8],
                                            short8 Wz[8], short8 Wn[8]) {
    const float* w0 = wsrc + (size_t)(j0 + l15) * HH;
    const float* w1 = wsrc + (size_t)(1024 + j0 + l15) * HH;
    const float* w2 = wsrc + (size_t)(2048 + j0 + l15) * HH;
#pragma unroll
    for (int s = 0; s < 8; ++s) {
        int k = kbase + s * 32 + q * 8;
        Wr[s] = pack8(&w0[k]);
        Wz[s] = pack8(&w1[k]);
        Wn[s] = pack8(&w2[k]);
    }
}

// Fused 2-layer persistent GRU, 128 blocks x 512 threads.
// R20 = EXACT R3 (R13) STRUCTURE -- the session's best (gru 1944 us) --
// with ONE isolated change: weights hoisted straight from f32 (3 cast
// kernels deleted). R19's half-split/setprio are reverted (half-split added
// a serial coherent RT per spin: -475 us). Flagless sentinel rings,
// role-split waves (0-3 compute / 4-7 gate), one 16KB batched spin per
// wave per step, 2 barriers/step.
__global__ __launch_bounds__(512) void gru_fused(
    const unsigned short* __restrict__ gx0, const float* __restrict__ whh0,
    const float* __restrict__ bhh0, const float* __restrict__ wih1,
    const float* __restrict__ whh1, const float* __restrict__ bih1,
    const float* __restrict__ bhh1, unsigned short* __restrict__ ring0,
    unsigned short* __restrict__ ring1, float* __restrict__ hn0,
    float* __restrict__ hn1) {
    __shared__ __align__(16) float red[8 * 6 * 64 * 4];  // 48 KB
    const int bid = blockIdx.x;
    const int tid = threadIdx.x;
    const int lane = tid & 63, wv = tid >> 6;
    const int l15 = lane & 15, q = lane >> 4;
    const bool isGate = (wv >= 4);
    const int wv3 = wv & 3;
    const int gtid = tid & 255;  // gate-thread id within waves 4-7
    const int gb = gtid >> 3, gjh = gtid & 7;
    const int gmi = gb >> 4, greg = gb & 3;
    const int grl = ((gb & 15) >> 2) * 16 + 2 * gjh;  // MFMA C-layout lane (i=0)

    if (bid < 64) {
        // ================= layer 0 =================
        const int j0 = bid * 16;
        const int kbase = wv3 * 256;
        short8 Wr[8], Wz[8], Wn[8];
        if (!isGate) hoist_w_f32(whh0, j0, l15, q, kbase, Wr, Wz, Wn);

        float bR[2], bZ[2], bN[2], hpriv[2] = {0.f, 0.f};
        unsigned int pxr = 0, pxz = 0, pxn = 0;
        const unsigned short* gxp = nullptr;
        if (isGate) {
            int jj = j0 + 2 * gjh;
#pragma unroll
            for (int i = 0; i < 2; ++i) {
                bR[i] = bhh0[jj + i];
                bZ[i] = bhh0[1024 + jj + i];
                bN[i] = bhh0[2048 + jj + i];
            }
            gxp = gx0 + (size_t)gb * TT * 3072 + jj;
            pxr = *(const unsigned int*)(gxp);
            pxz = *(const unsigned int*)(gxp + 1024);
            pxn = *(const unsigned int*)(gxp + 2048);
        }

        for (int t = 0; t <= TT; ++t) {
            floatx4 acc[6] = {};
            bool doW = false;
            if (!isGate) {
                if (t < TT) {  // produce acc(t) = Whh0 . h0(t)
                    uint4v r0[8], r1[8];
                    spin_load8(ring0 + (size_t)t * SLOT, kbase, l15, q, r0, r1);
                    mfma8(r0, r1, Wr, Wz, Wn, acc);
                    doW = true;
                }
            } else if (t > 0) {  // consume acc(t-1) -> h0(t) -> ring0 slot t
                unsigned int cxr = pxr, cxz = pxz, cxn = pxn;
                if (t < TT) {  // prefetch gx(t) early (used at t+1)
                    const unsigned short* g2 = gxp + (size_t)t * 3072;
                    pxr = *(const unsigned int*)(g2);
                    pxz = *(const unsigned int*)(g2 + 1024);
                    pxn = *(const unsigned int*)(g2 + 2048);
                }
                float hnew[2];
#pragma unroll
                for (int i = 0; i < 2; ++i) {
                    int rl = grl + i;
                    float pr[4], pz[4], pn[4];
#pragma unroll
                    for (int w = 0; w < 4; ++w) {
                        pr[w] = red[RSWZ(((w * 6 + gmi * 3 + 0) * 64 + rl) * 4 + greg)];
                        pz[w] = red[RSWZ(((w * 6 + gmi * 3 + 1) * 64 + rl) * 4 + greg)];
                        pn[w] = red[RSWZ(((w * 6 + gmi * 3 + 2) * 64 + rl) * 4 + greg)];
                    }
                    float gr = (pr[0] + pr[1]) + (pr[2] + pr[3]);
                    float gz = (pz[0] + pz[1]) + (pz[2] + pz[3]);
                    float gn = (pn[0] + pn[1]) + (pn[2] + pn[3]);
                    float xr = bf2f((unsigned short)(i ? (cxr >> 16) : (cxr & 0xffffu)));
                    float xz = bf2f((unsigned short)(i ? (cxz >> 16) : (cxz & 0xffffu)));
                    float xn = bf2f((unsigned short)(i ? (cxn >> 16) : (cxn & 0xffffu)));
                    float rg = 1.f / (1.f + __expf(-(xr + gr + bR[i])));
                    float zg = 1.f / (1.f + __expf(-(xz + gz + bZ[i])));
                    float ng = fast_tanh(xn + rg * (gn + bN[i]));
                    hnew[i] = (1.f - zg) * ng + zg * hpriv[i];
                    hpriv[i] = hnew[i];
                }
                unsigned int hpack =
                    (unsigned int)f2bf(hnew[0]) | ((unsigned int)f2bf(hnew[1]) << 16);
                unsigned int* dst =
                    (unsigned int*)(ring0 + (size_t)t * SLOT) + (bid << 8) + gtid;
                __hip_atomic_store(dst, hpack, __ATOMIC_RELAXED,
                                   __HIP_MEMORY_SCOPE_AGENT);
                if (t == TT) {
                    hn0[gb * HH + j0 + 2 * gjh] = hnew[0];
                    hn0[gb * HH + j0 + 2 * gjh + 1] = hnew[1];
                }
            }
            __syncthreads();  // red reads of step t-1 complete
            if (doW) {
#pragma unroll
                for (int tl = 0; tl < 6; ++tl)
                    *(floatx4*)&red[RSWZ(((wv3 * 6 + tl) * 64 + lane) * 4)] = acc[tl];
            }
            __syncthreads();  // red(t) ready for gate waves at t+1
        }
    } else {
        // ================= layer 1 =================
        const int b2 = bid - 64;
        const int j0 = b2 * 16;
        const int kbase = wv3 * 256;
        short8 Wr[8], Wz[8], Wn[8];
        // compute waves: whh1 (h-part); gate waves: wih1 (x-part)
        hoist_w_f32(isGate ? wih1 : whh1, j0, l15, q, kbase, Wr, Wz, Wn);

        float cR[2], cZ[2], cNx[2], cNh[2], hpriv[2] = {0.f, 0.f};
        if (isGate) {
            int jj = j0 + 2 * gjh;
#pragma unroll
            for (int i = 0; i < 2; ++i) {
                cR[i] = bih1[jj + i] + bhh1[jj + i];
                cZ[i] = bih1[1024 + jj + i] + bhh1[1024 + jj + i];
                cNx[i] = bih1[2048 + jj + i];
                cNh[i] = bhh1[2048 + jj + i];
            }
        }

        for (int t = 0; t <= TT; ++t) {
            floatx4 acc[6] = {};
            bool doW = false;
            if (!isGate) {
                if (t < TT) {  // h-part acc(t) = Whh1 . h1(t)
                    uint4v r0[8], r1[8];
                    spin_load8(ring1 + (size_t)t * SLOT, kbase, l15, q, r0, r1);
                    mfma8(r0, r1, Wr, Wz, Wn, acc);
                    doW = true;
                }
            } else {
                if (t > 0) {  // consume acc(t-1) -> h1(t) -> ring1 slot t
                    float hnew[2];
#pragma unroll
                    for (int i = 0; i < 2; ++i) {
                        int rl = grl + i;
                        float pr[8], pz[8], ph[4], px[4];
#pragma unroll
                        for (int w = 0; w < 8; ++w) {
                            pr[w] = red[RSWZ(((w * 6 + gmi * 3 + 0) * 64 + rl) * 4 + greg)];
                            pz[w] = red[RSWZ(((w * 6 + gmi * 3 + 1) * 64 + rl) * 4 + greg)];
                        }
#pragma unroll
                        for (int w = 0; w < 4; ++w)
                            ph[w] = red[RSWZ(((w * 6 + gmi * 3 + 2) * 64 + rl) * 4 + greg)];
#pragma unroll
                        for (int w = 4; w < 8; ++w)
                            px[w - 4] = red[RSWZ(((w * 6 + gmi * 3 + 2) * 64 + rl) * 4 + greg)];
                        float gr = tree8(pr), gz = tree8(pz);
                        float hn = (ph[0] + ph[1]) + (ph[2] + ph[3]);
                        float xn = (px[0] + px[1]) + (px[2] + px[3]);
                        float rg = 1.f / (1.f + __expf(-(gr + cR[i])));
                        float zg = 1.f / (1.f + __expf(-(gz + cZ[i])));
                        float ng = fast_tanh(xn + cNx[i] + rg * (hn + cNh[i]));
                        hnew[i] = (1.f - zg) * ng + zg * hpriv[i];
                        hpriv[i] = hnew[i];
                    }
                    unsigned int hpack =
                        (unsigned int)f2bf(hnew[0]) | ((unsigned int)f2bf(hnew[1]) << 16);
                    unsigned int* dst =
                        (unsigned int*)(ring1 + (size_t)t * SLOT) + (b2 << 8) + gtid;
                    __hip_atomic_store(dst, hpack, __ATOMIC_RELAXED,
                                       __HIP_MEMORY_SCOPE_AGENT);
                    if (t == TT) {
                        hn1[gb * HH + j0 + 2 * gjh] = hnew[0];
                        hn1[gb * HH + j0 + 2 * gjh + 1] = hnew[1];
                    }
                }
                if (t < TT) {  // x-part acc(t) = Wih1 . x1(t), x1(t) = ring0 slot t+1
                    uint4v r0[8], r1[8];
                    spin_load8(ring0 + (size_t)(t + 1) * SLOT, kbase, l15, q, r0, r1);
                    mfma8(r0, r1, Wr, Wz, Wn, acc);
                    doW = true;
                }
            }
            __syncthreads();  // red reads of step t-1 complete
            if (doW) {
#pragma unroll
                for (int tl = 0; tl < 6; ++tl)
                    *(floatx4*)&red[RSWZ(((wv * 6 + tl) * 64 + lane) * 4)] = acc[tl];
            }
            __syncthreads();  // red(t) ready
        }
    }
}

// h1bf is ring1 slot TT in chunked layout: (b,k) at (k>>4)*512 + b*16 + (k&15)
__global__ void fc_out(const unsigned short* __restrict__ h1bf,
                       const float* __restrict__ fcw, const float* __restrict__ fcb,
                       float* __restrict__ out) {
    int b = blockIdx.x, o = threadIdx.x;  // 32 x 256
    const float* wr = fcw + (size_t)o * HH;
    float acc = fcb[o];
    for (int k = 0; k < HH; k += 16) {
        const unsigned short* hp = h1bf + ((k >> 4) << 9) + (b << 4);
#pragma unroll
        for (int i = 0; i < 16; ++i) acc += bf2f(hp[i]) * wr[k + i];
    }
    out[b * OUTW + o] = 1.f / (1.f + expf(-acc));
}

extern "C" void kernel_launch(void* const* d_in, const int* in_sizes, int n_in,
                              void* d_out, int out_size, void* d_ws, size_t ws_size,
                              hipStream_t stream) {
    (void)in_sizes; (void)n_in; (void)out_size; (void)ws_size;
    const float* input = (const float*)d_in[0];
    const float* w_ih0 = (const float*)d_in[1];
    const float* w_hh0 = (const float*)d_in[2];
    const float* b_ih0 = (const float*)d_in[3];
    const float* b_hh0 = (const float*)d_in[4];
    const float* w_ih1 = (const float*)d_in[5];
    const float* w_hh1 = (const float*)d_in[6];
    const float* b_ih1 = (const float*)d_in[7];
    const float* b_hh1 = (const float*)d_in[8];
    const float* fc_w = (const float*)d_in[9];
    const float* fc_b = (const float*)d_in[10];
    float* out = (float*)d_out;

    char* ws = (char*)d_ws;
    size_t off = 0;
    auto alloc = [&](size_t bytes) {
        void* p = ws + off;
        off += (bytes + 255) & ~(size_t)255;
        return p;
    };
    unsigned short* ring0 = (unsigned short*)alloc((size_t)(TT + 1) * SLOT * 2);
    unsigned short* ring1 = (unsigned short*)alloc((size_t)(TT + 1) * SLOT * 2);
    unsigned short* gx0 = (unsigned short*)alloc((size_t)16384 * 3072 * 2);
    unsigned short* in_bf = (unsigned short*)alloc((size_t)16384 * 256 * 2);
    unsigned short* wih0_bf = (unsigned short*)alloc((size_t)3072 * 256 * 2);

    // Pre-fill both rings with the sentinel (rings are adjacent in ws).
    // Slot 0 of each ring is then zeroed (h(0) = 0).
    {
        size_t total_bytes = (size_t)2 * (TT + 1) * SLOT * 2;
        fill_sent<<<1024, 256, 0, stream>>>((uint4v*)ring0, total_bytes / 16);
    }

    cast_f32_bf16<<<256, 256, 0, stream>>>(input, in_bf, 16384 * 256);
    cast_f32_bf16<<<64, 256, 0, stream>>>(w_ih0, wih0_bf, 3072 * 256);

    hipMemsetAsync(ring0, 0, (size_t)SLOT * 2, stream);  // h0(0) = 0
    hipMemsetAsync(ring1, 0, (size_t)SLOT * 2, stream);  // h1(0) = 0

    // gx0 = input @ w_ih0^T + b_ih0 (layer-1 projections fused into gru kernel)
    gemm_gx<256><<<12288, 256, 0, stream>>>(in_bf, wih0_bf, b_ih0, gx0);

    gru_fused<<<128, 512, 0, stream>>>(gx0, w_hh0, b_hh0, w_ih1, w_hh1, b_ih1,
                                       b_hh1, ring0, ring1, out + 8192,
                                       out + 8192 + 32768);

    // ---- FC + sigmoid on h_last of layer 1 (ring1 slot TT, chunked) ----
    fc_out<<<32, 256, 0, stream>>>(ring1 + (size_t)TT * SLOT, fc_w, fc_b, out);
}

// Round 11
// 2155.732 us; speedup vs baseline: 1.5219x; 1.5219x over previous
//
#include <hip/hip_runtime.h>

#define BB 32
#define TT 512
#define INW 256
#define HH 1024
#define OUTW 256
#define SLOT 32768  // ushorts per ring slot; layout [64 chunks][32 b][16 j]
// 3H = 3072

typedef __attribute__((ext_vector_type(8))) short short8;
typedef __attribute__((ext_vector_type(4))) float floatx4;
typedef __attribute__((ext_vector_type(4))) unsigned int uint4v;

// Sentinel: bf16 +inf. Real h values satisfy |h| < 1 (tanh/sigmoid
// contraction), so a ring dword (two bf16 h) never equals 0x7F807F80.
#define SENT 0x7F807F80u

// LDS reduce swizzle: XOR dword-index bits 2-3 with bits 5-6 (source lane).
#define RSWZ(i) ((i) ^ ((((i) >> 5) & 3) << 2))

__device__ __forceinline__ unsigned short f2bf(float f) {
    unsigned int u = __float_as_uint(f);
    u = (u + 0x7fffu + ((u >> 16) & 1u)) >> 16;
    return (unsigned short)u;
}
__device__ __forceinline__ float bf2f(unsigned short h) {
    return __uint_as_float(((unsigned int)h) << 16);
}
__device__ __forceinline__ float fast_tanh(float x) {
    return 2.f / (1.f + __expf(-2.f * x)) - 1.f;
}
__device__ __forceinline__ float tree8(const float* p) {
    return ((p[0] + p[1]) + (p[2] + p[3])) + ((p[4] + p[5]) + (p[6] + p[7]));
}

__global__ void cast_f32_bf16(const float* __restrict__ src,
                              unsigned short* __restrict__ dst, int n) {
    int i = blockIdx.x * blockDim.x + threadIdx.x;
    int stride = gridDim.x * blockDim.x;
    for (; i < n; i += stride) dst[i] = f2bf(src[i]);
}

__global__ void fill_sent(uint4v* __restrict__ dst, size_t n4) {
    size_t i = (size_t)blockIdx.x * blockDim.x + threadIdx.x;
    size_t stride = (size_t)gridDim.x * blockDim.x;
    uint4v v = {SENT, SENT, SENT, SENT};
    for (; i < n4; i += stride) dst[i] = v;
}

// C_bf16[M x 3072] = X_bf16[M x K] @ W_bf16[3072 x K]^T + bias_f32
template <int K>
__global__ __launch_bounds__(256) void gemm_gx(const unsigned short* __restrict__ X,
                                               const unsigned short* __restrict__ W,
                                               const float* __restrict__ bias,
                                               unsigned short* __restrict__ Cout) {
    __shared__ __align__(16) unsigned short As[64 * 40];
    __shared__ __align__(16) unsigned short Bs[64 * 40];
    int bid = blockIdx.x;
    int tn = bid % 48, tm = bid / 48;
    int tid = threadIdx.x;
    int lane = tid & 63, wv = tid >> 6;
    int wm = wv >> 1, wn = wv & 1;
    int l15 = lane & 15, q = lane >> 4;
    floatx4 acc[2][2] = {};
    int r = tid >> 2, kq = (tid & 3) * 8;
    const unsigned short* xrow = X + (size_t)(tm * 64 + r) * K;
    const unsigned short* wrow = W + (size_t)(tn * 64 + r) * K;
    const int NK = K / 32;
    for (int kk = 0; kk < NK; ++kk) {
        int k0 = kk * 32;
        *(short8*)&As[r * 40 + kq] = *(const short8*)&xrow[k0 + kq];
        *(short8*)&Bs[r * 40 + kq] = *(const short8*)&wrow[k0 + kq];
        __syncthreads();
        short8 a0 = *(const short8*)&As[(wm * 32 + l15) * 40 + q * 8];
        short8 a1 = *(const short8*)&As[(wm * 32 + 16 + l15) * 40 + q * 8];
        short8 b0 = *(const short8*)&Bs[(wn * 32 + l15) * 40 + q * 8];
        short8 b1 = *(const short8*)&Bs[(wn * 32 + 16 + l15) * 40 + q * 8];
        acc[0][0] = __builtin_amdgcn_mfma_f32_16x16x32_bf16(a0, b0, acc[0][0], 0, 0, 0);
        acc[0][1] = __builtin_amdgcn_mfma_f32_16x16x32_bf16(a0, b1, acc[0][1], 0, 0, 0);
        acc[1][0] = __builtin_amdgcn_mfma_f32_16x16x32_bf16(a1, b0, acc[1][0], 0, 0, 0);
        acc[1][1] = __builtin_amdgcn_mfma_f32_16x16x32_bf16(a1, b1, acc[1][1], 0, 0, 0);
        __syncthreads();
    }
    for (int mi = 0; mi < 2; ++mi)
        for (int ni = 0; ni < 2; ++ni) {
            int col = tn * 64 + wn * 32 + ni * 16 + l15;
            float bv = bias[col];
            int row0 = tm * 64 + wm * 32 + mi * 16 + q * 4;
            for (int rr = 0; rr < 4; ++rr) {
                Cout[(size_t)(row0 + rr) * 3072 + col] = f2bf(acc[mi][ni][rr] + bv);
            }
        }
}

// Verified spin-fetch of 8 A-fragment pairs: the full 16 KB K-slice issued
// in one batch (single coherent round trip when ready). Bypass loads are
// the only synchronization: retry until no dword is the sentinel. Register
// results tied through the waitcnt so the compiler cannot hoist compares.
__device__ __forceinline__ void spin_load8(const unsigned short* base, int kbase,
                                           int l15, int q, uint4v r0[8],
                                           uint4v r1[8]) {
    const unsigned short* ap[8];
#pragma unroll
    for (int s = 0; s < 8; ++s) {
        int k = kbase + s * 32 + q * 8;
        ap[s] = base + ((k >> 4) << 9) + (l15 << 4) + (k & 15);
    }
    while (true) {
#pragma unroll
        for (int s = 0; s < 8; ++s) {
            asm volatile("global_load_dwordx4 %0, %1, off sc0 sc1"
                         : "=&v"(r0[s]) : "v"(ap[s]));
            asm volatile("global_load_dwordx4 %0, %1, off offset:512 sc0 sc1"
                         : "=&v"(r1[s]) : "v"(ap[s]));
        }
        asm volatile("s_waitcnt vmcnt(0)"
                     : "+v"(r0[0]), "+v"(r0[1]), "+v"(r0[2]), "+v"(r0[3]),
                       "+v"(r0[4]), "+v"(r0[5]), "+v"(r0[6]), "+v"(r0[7]),
                       "+v"(r1[0]), "+v"(r1[1]), "+v"(r1[2]), "+v"(r1[3]),
                       "+v"(r1[4]), "+v"(r1[5]), "+v"(r1[6]), "+v"(r1[7])
                     :: "memory");
        unsigned bad = 0;
#pragma unroll
        for (int s = 0; s < 8; ++s) {
            bad |= (unsigned)(r0[s][0] == SENT) | (unsigned)(r0[s][1] == SENT) |
                   (unsigned)(r0[s][2] == SENT) | (unsigned)(r0[s][3] == SENT);
            bad |= (unsigned)(r1[s][0] == SENT) | (unsigned)(r1[s][1] == SENT) |
                   (unsigned)(r1[s][2] == SENT) | (unsigned)(r1[s][3] == SENT);
        }
        if (!__any((int)bad)) break;
    }
}

__device__ __forceinline__ void mfma8(const uint4v r0[8], const uint4v r1[8],
                                      const short8 Wr[8], const short8 Wz[8],
                                      const short8 Wn[8], floatx4 acc[6]) {
#pragma unroll
    for (int s = 0; s < 8; ++s) {
        short8 a0 = __builtin_bit_cast(short8, r0[s]);
        short8 a1 = __builtin_bit_cast(short8, r1[s]);
        acc[0] = __builtin_amdgcn_mfma_f32_16x16x32_bf16(a0, Wr[s], acc[0], 0, 0, 0);
        acc[1] = __builtin_amdgcn_mfma_f32_16x16x32_bf16(a0, Wz[s], acc[1], 0, 0, 0);
        acc[2] = __builtin_amdgcn_mfma_f32_16x16x32_bf16(a0, Wn[s], acc[2], 0, 0, 0);
        acc[3] = __builtin_amdgcn_mfma_f32_16x16x32_bf16(a1, Wr[s], acc[3], 0, 0, 0);
        acc[4] = __builtin_amdgcn_mfma_f32_16x16x32_bf16(a1, Wz[s], acc[4], 0, 0, 0);
        acc[5] = __builtin_amdgcn_mfma_f32_16x16x32_bf16(a1, Wn[s], acc[5], 0, 0, 0);
    }
}

__device__ __forceinline__ void hoist_w(const unsigned short* wsrc, int j0, int l15,
                                        int q, int kbase, short8 Wr[8], short8 Wz[8],
                                        short8 Wn[8]) {
    const unsigned short* w0 = wsrc + (size_t)(j0 + l15) * HH;
    const unsigned short* w1 = wsrc + (size_t)(1024 + j0 + l15) * HH;
    const unsigned short* w2 = wsrc + (size_t)(2048 + j0 + l15) * HH;
#pragma unroll
    for (int s = 0; s < 8; ++s) {
        int k = kbase + s * 32 + q * 8;
        Wr[s] = *(const short8*)&w0[k];
        Wz[s] = *(const short8*)&w1[k];
        Wn[s] = *(const short8*)&w2[k];
    }
}

// Fused 2-layer persistent GRU, 128 blocks x 512 threads.
// R21: EXACT R3/R13 RESUBMIT -- the session champion (gru 1944 us, total
// 2200 us). R20's f32-weight hoist regressed to 3071 us: gru read the COLD
// original input buffers in-kernel (possibly slow-path memory) instead of
// workspace bf16 copies freshly written by the cast kernels (L2/L3-warm).
// Pre-cast weights are restored. Flagless sentinel rings, role-split waves
// (0-3 compute / 4-7 gate+x-part), one batched 16 KB spin per wave per
// step, 2 barriers/step.
__global__ __launch_bounds__(512) void gru_fused(
    const unsigned short* __restrict__ gx0, const unsigned short* __restrict__ whh0,
    const float* __restrict__ bhh0, const unsigned short* __restrict__ wih1,
    const unsigned short* __restrict__ whh1, const float* __restrict__ bih1,
    const float* __restrict__ bhh1, unsigned short* __restrict__ ring0,
    unsigned short* __restrict__ ring1, float* __restrict__ hn0,
    float* __restrict__ hn1) {
    __shared__ __align__(16) float red[8 * 6 * 64 * 4];  // 48 KB
    const int bid = blockIdx.x;
    const int tid = threadIdx.x;
    const int lane = tid & 63, wv = tid >> 6;
    const int l15 = lane & 15, q = lane >> 4;
    const bool isGate = (wv >= 4);
    const int wv3 = wv & 3;
    const int gtid = tid & 255;  // gate-thread id within waves 4-7
    const int gb = gtid >> 3, gjh = gtid & 7;
    const int gmi = gb >> 4, greg = gb & 3;
    const int grl = ((gb & 15) >> 2) * 16 + 2 * gjh;  // MFMA C-layout lane (i=0)

    if (bid < 64) {
        // ================= layer 0 =================
        const int j0 = bid * 16;
        const int kbase = wv3 * 256;
        short8 Wr[8], Wz[8], Wn[8];
        if (!isGate) hoist_w(whh0, j0, l15, q, kbase, Wr, Wz, Wn);

        float bR[2], bZ[2], bN[2], hpriv[2] = {0.f, 0.f};
        unsigned int pxr = 0, pxz = 0, pxn = 0;
        const unsigned short* gxp = nullptr;
        if (isGate) {
            int jj = j0 + 2 * gjh;
#pragma unroll
            for (int i = 0; i < 2; ++i) {
                bR[i] = bhh0[jj + i];
                bZ[i] = bhh0[1024 + jj + i];
                bN[i] = bhh0[2048 + jj + i];
            }
            gxp = gx0 + (size_t)gb * TT * 3072 + jj;
            pxr = *(const unsigned int*)(gxp);
            pxz = *(const unsigned int*)(gxp + 1024);
            pxn = *(const unsigned int*)(gxp + 2048);
        }

        for (int t = 0; t <= TT; ++t) {
            floatx4 acc[6] = {};
            bool doW = false;
            if (!isGate) {
                if (t < TT) {  // produce acc(t) = Whh0 . h0(t)
                    uint4v r0[8], r1[8];
                    spin_load8(ring0 + (size_t)t * SLOT, kbase, l15, q, r0, r1);
                    mfma8(r0, r1, Wr, Wz, Wn, acc);
                    doW = true;
                }
            } else if (t > 0) {  // consume acc(t-1) -> h0(t) -> ring0 slot t
                unsigned int cxr = pxr, cxz = pxz, cxn = pxn;
                if (t < TT) {  // prefetch gx(t) early (used at t+1)
                    const unsigned short* g2 = gxp + (size_t)t * 3072;
                    pxr = *(const unsigned int*)(g2);
                    pxz = *(const unsigned int*)(g2 + 1024);
                    pxn = *(const unsigned int*)(g2 + 2048);
                }
                float hnew[2];
#pragma unroll
                for (int i = 0; i < 2; ++i) {
                    int rl = grl + i;
                    float pr[4], pz[4], pn[4];
#pragma unroll
                    for (int w = 0; w < 4; ++w) {
                        pr[w] = red[RSWZ(((w * 6 + gmi * 3 + 0) * 64 + rl) * 4 + greg)];
                        pz[w] = red[RSWZ(((w * 6 + gmi * 3 + 1) * 64 + rl) * 4 + greg)];
                        pn[w] = red[RSWZ(((w * 6 + gmi * 3 + 2) * 64 + rl) * 4 + greg)];
                    }
                    float gr = (pr[0] + pr[1]) + (pr[2] + pr[3]);
                    float gz = (pz[0] + pz[1]) + (pz[2] + pz[3]);
                    float gn = (pn[0] + pn[1]) + (pn[2] + pn[3]);
                    float xr = bf2f((unsigned short)(i ? (cxr >> 16) : (cxr & 0xffffu)));
                    float xz = bf2f((unsigned short)(i ? (cxz >> 16) : (cxz & 0xffffu)));
                    float xn = bf2f((unsigned short)(i ? (cxn >> 16) : (cxn & 0xffffu)));
                    float rg = 1.f / (1.f + __expf(-(xr + gr + bR[i])));
                    float zg = 1.f / (1.f + __expf(-(xz + gz + bZ[i])));
                    float ng = fast_tanh(xn + rg * (gn + bN[i]));
                    hnew[i] = (1.f - zg) * ng + zg * hpriv[i];
                    hpriv[i] = hnew[i];
                }
                unsigned int hpack =
                    (unsigned int)f2bf(hnew[0]) | ((unsigned int)f2bf(hnew[1]) << 16);
                unsigned int* dst =
                    (unsigned int*)(ring0 + (size_t)t * SLOT) + (bid << 8) + gtid;
                __hip_atomic_store(dst, hpack, __ATOMIC_RELAXED,
                                   __HIP_MEMORY_SCOPE_AGENT);
                if (t == TT) {
                    hn0[gb * HH + j0 + 2 * gjh] = hnew[0];
                    hn0[gb * HH + j0 + 2 * gjh + 1] = hnew[1];
                }
            }
            __syncthreads();  // red reads of step t-1 complete
            if (doW) {
#pragma unroll
                for (int tl = 0; tl < 6; ++tl)
                    *(floatx4*)&red[RSWZ(((wv3 * 6 + tl) * 64 + lane) * 4)] = acc[tl];
            }
            __syncthreads();  // red(t) ready for gate waves at t+1
        }
    } else {
        // ================= layer 1 =================
        const int b2 = bid - 64;
        const int j0 = b2 * 16;
        const int kbase = wv3 * 256;
        short8 Wr[8], Wz[8], Wn[8];
        // compute waves: whh1 (h-part); gate waves: wih1 (x-part)
        hoist_w(isGate ? wih1 : whh1, j0, l15, q, kbase, Wr, Wz, Wn);

        float cR[2], cZ[2], cNx[2], cNh[2], hpriv[2] = {0.f, 0.f};
        if (isGate) {
            int jj = j0 + 2 * gjh;
#pragma unroll
            for (int i = 0; i < 2; ++i) {
                cR[i] = bih1[jj + i] + bhh1[jj + i];
                cZ[i] = bih1[1024 + jj + i] + bhh1[1024 + jj + i];
                cNx[i] = bih1[2048 + jj + i];
                cNh[i] = bhh1[2048 + jj + i];
            }
        }

        for (int t = 0; t <= TT; ++t) {
            floatx4 acc[6] = {};
            bool doW = false;
            if (!isGate) {
                if (t < TT) {  // h-part acc(t) = Whh1 . h1(t)
                    uint4v r0[8], r1[8];
                    spin_load8(ring1 + (size_t)t * SLOT, kbase, l15, q, r0, r1);
                    mfma8(r0, r1, Wr, Wz, Wn, acc);
                    doW = true;
                }
            } else {
                if (t > 0) {  // consume acc(t-1) -> h1(t) -> ring1 slot t
                    float hnew[2];
#pragma unroll
                    for (int i = 0; i < 2; ++i) {
                        int rl = grl + i;
                        float pr[8], pz[8], ph[4], px[4];
#pragma unroll
                        for (int w = 0; w < 8; ++w) {
                            pr[w] = red[RSWZ(((w * 6 + gmi * 3 + 0) * 64 + rl) * 4 + greg)];
                            pz[w] = red[RSWZ(((w * 6 + gmi * 3 + 1) * 64 + rl) * 4 + greg)];
                        }
#pragma unroll
                        for (int w = 0; w < 4; ++w)
                            ph[w] = red[RSWZ(((w * 6 + gmi * 3 + 2) * 64 + rl) * 4 + greg)];
#pragma unroll
                        for (int w = 4; w < 8; ++w)
                            px[w - 4] = red[RSWZ(((w * 6 + gmi * 3 + 2) * 64 + rl) * 4 + greg)];
                        float gr = tree8(pr), gz = tree8(pz);
                        float hn = (ph[0] + ph[1]) + (ph[2] + ph[3]);
                        float xn = (px[0] + px[1]) + (px[2] + px[3]);
                        float rg = 1.f / (1.f + __expf(-(gr + cR[i])));
                        float zg = 1.f / (1.f + __expf(-(gz + cZ[i])));
                        float ng = fast_tanh(xn + cNx[i] + rg * (hn + cNh[i]));
                        hnew[i] = (1.f - zg) * ng + zg * hpriv[i];
                        hpriv[i] = hnew[i];
                    }
                    unsigned int hpack =
                        (unsigned int)f2bf(hnew[0]) | ((unsigned int)f2bf(hnew[1]) << 16);
                    unsigned int* dst =
                        (unsigned int*)(ring1 + (size_t)t * SLOT) + (b2 << 8) + gtid;
                    __hip_atomic_store(dst, hpack, __ATOMIC_RELAXED,
                                       __HIP_MEMORY_SCOPE_AGENT);
                    if (t == TT) {
                        hn1[gb * HH + j0 + 2 * gjh] = hnew[0];
                        hn1[gb * HH + j0 + 2 * gjh + 1] = hnew[1];
                    }
                }
                if (t < TT) {  // x-part acc(t) = Wih1 . x1(t), x1(t) = ring0 slot t+1
                    uint4v r0[8], r1[8];
                    spin_load8(ring0 + (size_t)(t + 1) * SLOT, kbase, l15, q, r0, r1);
                    mfma8(r0, r1, Wr, Wz, Wn, acc);
                    doW = true;
                }
            }
            __syncthreads();  // red reads of step t-1 complete
            if (doW) {
#pragma unroll
                for (int tl = 0; tl < 6; ++tl)
                    *(floatx4*)&red[RSWZ(((wv * 6 + tl) * 64 + lane) * 4)] = acc[tl];
            }
            __syncthreads();  // red(t) ready
        }
    }
}

// h1bf is ring1 slot TT in chunked layout: (b,k) at (k>>4)*512 + b*16 + (k&15)
__global__ void fc_out(const unsigned short* __restrict__ h1bf,
                       const float* __restrict__ fcw, const float* __restrict__ fcb,
                       float* __restrict__ out) {
    int b = blockIdx.x, o = threadIdx.x;  // 32 x 256
    const float* wr = fcw + (size_t)o * HH;
    float acc = fcb[o];
    for (int k = 0; k < HH; k += 16) {
        const unsigned short* hp = h1bf + ((k >> 4) << 9) + (b << 4);
#pragma unroll
        for (int i = 0; i < 16; ++i) acc += bf2f(hp[i]) * wr[k + i];
    }
    out[b * OUTW + o] = 1.f / (1.f + expf(-acc));
}

extern "C" void kernel_launch(void* const* d_in, const int* in_sizes, int n_in,
                              void* d_out, int out_size, void* d_ws, size_t ws_size,
                              hipStream_t stream) {
    (void)in_sizes; (void)n_in; (void)out_size; (void)ws_size;
    const float* input = (const float*)d_in[0];
    const float* w_ih0 = (const float*)d_in[1];
    const float* w_hh0 = (const float*)d_in[2];
    const float* b_ih0 = (const float*)d_in[3];
    const float* b_hh0 = (const float*)d_in[4];
    const float* w_ih1 = (const float*)d_in[5];
    const float* w_hh1 = (const float*)d_in[6];
    const float* b_ih1 = (const float*)d_in[7];
    const float* b_hh1 = (const float*)d_in[8];
    const float* fc_w = (const float*)d_in[9];
    const float* fc_b = (const float*)d_in[10];
    float* out = (float*)d_out;

    char* ws = (char*)d_ws;
    size_t off = 0;
    auto alloc = [&](size_t bytes) {
        void* p = ws + off;
        off += (bytes + 255) & ~(size_t)255;
        return p;
    };
    unsigned short* ring0 = (unsigned short*)alloc((size_t)(TT + 1) * SLOT * 2);
    unsigned short* ring1 = (unsigned short*)alloc((size_t)(TT + 1) * SLOT * 2);
    unsigned short* gx0 = (unsigned short*)alloc((size_t)16384 * 3072 * 2);
    unsigned short* in_bf = (unsigned short*)alloc((size_t)16384 * 256 * 2);
    unsigned short* wih0_bf = (unsigned short*)alloc((size_t)3072 * 256 * 2);
    unsigned short* whh0_bf = (unsigned short*)alloc((size_t)3072 * 1024 * 2);
    unsigned short* wih1_bf = (unsigned short*)alloc((size_t)3072 * 1024 * 2);
    unsigned short* whh1_bf = (unsigned short*)alloc((size_t)3072 * 1024 * 2);

    // Pre-fill both rings with the sentinel (rings are adjacent in ws).
    // Slot 0 of each ring is then zeroed (h(0) = 0).
    {
        size_t total_bytes = (size_t)2 * (TT + 1) * SLOT * 2;
        fill_sent<<<1024, 256, 0, stream>>>((uint4v*)ring0, total_bytes / 16);
    }

    cast_f32_bf16<<<256, 256, 0, stream>>>(input, in_bf, 16384 * 256);
    cast_f32_bf16<<<64, 256, 0, stream>>>(w_ih0, wih0_bf, 3072 * 256);
    cast_f32_bf16<<<256, 256, 0, stream>>>(w_hh0, whh0_bf, 3072 * 1024);
    cast_f32_bf16<<<256, 256, 0, stream>>>(w_ih1, wih1_bf, 3072 * 1024);
    cast_f32_bf16<<<256, 256, 0, stream>>>(w_hh1, whh1_bf, 3072 * 1024);

    hipMemsetAsync(ring0, 0, (size_t)SLOT * 2, stream);  // h0(0) = 0
    hipMemsetAsync(ring1, 0, (size_t)SLOT * 2, stream);  // h1(0) = 0

    // gx0 = input @ w_ih0^T + b_ih0 (layer-1 projections fused into gru kernel)
    gemm_gx<256><<<12288, 256, 0, stream>>>(in_bf, wih0_bf, b_ih0, gx0);

    gru_fused<<<128, 512, 0, stream>>>(gx0, whh0_bf, b_hh0, wih1_bf, whh1_bf, b_ih1,
                                       b_hh1, ring0, ring1, out + 8192,
                                       out + 8192 + 32768);

    // ---- FC + sigmoid on h_last of layer 1 (ring1 slot TT, chunked) ----
    fc_out<<<32, 256, 0, stream>>>(ring1 + (size_t)TT * SLOT, fc_w, fc_b, out);
}